// Round 1
// baseline (55.195 us; speedup 1.0000x reference)
//
#include <hip/hip_runtime.h>

#define NPTS 4096
#define BATCH 8
#define BLK 256
#define BLOCKS_PER_BATCH (NPTS / BLK)              // 16
#define BLOCKS_PER_PASS (BATCH * BLOCKS_PER_BATCH) // 128
#define TOTAL_BLOCKS (2 * BLOCKS_PER_PASS)         // 256

// Pass 0: each thread owns a pred point, min over gt staged in LDS.
// Pass 1: each thread owns a gt point, min over pred staged in LDS.
// LDS entry: (-2*x, -2*y, -2*z, ||pt||^2)  -> inner loop is 3 FMA + 1 min:
//   D = pn + (gn - 2 p.g);  pn added after the min (wave-constant per thread).
__global__ __launch_bounds__(BLK) void chamfer_min_kernel(
    const float* __restrict__ pred,   // [B,3,N]
    const float* __restrict__ gt,     // [B,M,3]
    float* __restrict__ partial)      // [TOTAL_BLOCKS]
{
    __shared__ float4 s[NPTS];        // 64 KB
    __shared__ float red[BLK / 64];

    const int bid  = blockIdx.x;
    const int pass = bid / BLOCKS_PER_PASS;
    const int r    = bid - pass * BLOCKS_PER_PASS;
    const int b    = r / BLOCKS_PER_BATCH;
    const int j    = r - b * BLOCKS_PER_BATCH;
    const int t    = threadIdx.x;

    const float* p = pred + (size_t)b * 3 * NPTS;
    const float* g = gt   + (size_t)b * NPTS * 3;

    // Stage the "other" point set into LDS with -2 prescale + norm.
    if (pass == 0) {
        for (int i = t; i < NPTS; i += BLK) {
            float gx = g[i * 3 + 0], gy = g[i * 3 + 1], gz = g[i * 3 + 2];
            s[i] = make_float4(-2.f * gx, -2.f * gy, -2.f * gz,
                               fmaf(gx, gx, fmaf(gy, gy, gz * gz)));
        }
    } else {
        for (int i = t; i < NPTS; i += BLK) {
            float px = p[i], py = p[NPTS + i], pz = p[2 * NPTS + i];
            s[i] = make_float4(-2.f * px, -2.f * py, -2.f * pz,
                               fmaf(px, px, fmaf(py, py, pz * pz)));
        }
    }
    __syncthreads();

    // Own point (coalesced loads in both layouts).
    const int idx = j * BLK + t;
    float x, y, z;
    if (pass == 0) {
        x = p[idx]; y = p[NPTS + idx]; z = p[2 * NPTS + idx];
    } else {
        x = g[idx * 3 + 0]; y = g[idx * 3 + 1]; z = g[idx * 3 + 2];
    }
    const float n2 = fmaf(x, x, fmaf(y, y, z * z));

    // 4 independent min chains to break the dependent-min latency chain.
    float m0 = 3.4e38f, m1 = 3.4e38f, m2 = 3.4e38f, m3 = 3.4e38f;
    #pragma unroll 4
    for (int m = 0; m < NPTS; m += 4) {
        float4 q0 = s[m + 0];
        float4 q1 = s[m + 1];
        float4 q2 = s[m + 2];
        float4 q3 = s[m + 3];
        m0 = fminf(m0, fmaf(x, q0.x, fmaf(y, q0.y, fmaf(z, q0.z, q0.w))));
        m1 = fminf(m1, fmaf(x, q1.x, fmaf(y, q1.y, fmaf(z, q1.z, q1.w))));
        m2 = fminf(m2, fmaf(x, q2.x, fmaf(y, q2.y, fmaf(z, q2.z, q2.w))));
        m3 = fminf(m3, fmaf(x, q3.x, fmaf(y, q3.y, fmaf(z, q3.z, q3.w))));
    }
    float mn = n2 + fminf(fminf(m0, m1), fminf(m2, m3));

    // Deterministic block reduction: wave shuffle + LDS.
    float sum = mn;
    #pragma unroll
    for (int off = 32; off > 0; off >>= 1)
        sum += __shfl_down(sum, off, 64);
    if ((t & 63) == 0) red[t >> 6] = sum;
    __syncthreads();
    if (t == 0)
        partial[bid] = red[0] + red[1] + red[2] + red[3];
}

__global__ __launch_bounds__(TOTAL_BLOCKS) void chamfer_final_kernel(
    const float* __restrict__ partial, float* __restrict__ out)
{
    __shared__ float red[TOTAL_BLOCKS / 64];
    const int t = threadIdx.x;
    float v = partial[t];
    #pragma unroll
    for (int off = 32; off > 0; off >>= 1)
        v += __shfl_down(v, off, 64);
    if ((t & 63) == 0) red[t >> 6] = v;
    __syncthreads();
    if (t == 0) {
        float s = 0.f;
        #pragma unroll
        for (int w = 0; w < TOTAL_BLOCKS / 64; ++w) s += red[w];
        // loss = (sum dist1 + sum dist2) / (NPTS * BATCH)  (N == M)
        out[0] = s * (1.0f / ((float)NPTS * (float)BATCH));
    }
}

extern "C" void kernel_launch(void* const* d_in, const int* in_sizes, int n_in,
                              void* d_out, int out_size, void* d_ws, size_t ws_size,
                              hipStream_t stream) {
    const float* pred = (const float*)d_in[0];  // [8,3,4096]
    const float* gt   = (const float*)d_in[1];  // [8,4096,3]
    float* out = (float*)d_out;
    float* partial = (float*)d_ws;              // TOTAL_BLOCKS floats

    chamfer_min_kernel<<<TOTAL_BLOCKS, BLK, 0, stream>>>(pred, gt, partial);
    chamfer_final_kernel<<<1, TOTAL_BLOCKS, 0, stream>>>(partial, out);
}

// Round 2
// 32.152 us; speedup vs baseline: 1.7167x; 1.7167x over previous
//
#include <hip/hip_runtime.h>

#define NPTS 4096
#define BATCH 8
#define BLK 256
#define P 4                              // own points per thread
#define CHUNK 512                        // staged points per block (8 KB LDS)
#define NCHUNK (NPTS / CHUNK)            // 8
#define OWN_PER_BLK (BLK * P)            // 1024
#define OWN_BLKS (NPTS / OWN_PER_BLK)    // 4 per batch
#define BLOCKS_PER_PASS (BATCH * OWN_BLKS * NCHUNK)  // 256
#define TOTAL_BLOCKS (2 * BLOCKS_PER_PASS)           // 512
#define HALF_OWN (BATCH * NPTS)          // 32768
#define TOTAL_OWN (2 * HALF_OWN)         // 65536
#define COMBINE_BLOCKS (TOTAL_OWN / BLK) // 256

// LDS entry: (-2x, -2y, -2z, ||q||^2). D = ||p||^2 + (||q||^2 - 2 p.q);
// ||p||^2 is thread-constant, added after the min.
__global__ __launch_bounds__(BLK) void chamfer_partial_kernel(
    const float* __restrict__ pred,   // [B,3,N]
    const float* __restrict__ gt,     // [B,M,3]
    float* __restrict__ partial)      // [NCHUNK][TOTAL_OWN]
{
    __shared__ float4 s[CHUNK];

    const int bid  = blockIdx.x;
    const int pass = bid / BLOCKS_PER_PASS;
    int r = bid - pass * BLOCKS_PER_PASS;
    const int c = r % NCHUNK;
    r /= NCHUNK;
    const int b = r / OWN_BLKS;
    const int j = r - b * OWN_BLKS;
    const int t = threadIdx.x;

    const float* p = pred + (size_t)b * 3 * NPTS;
    const float* g = gt   + (size_t)b * NPTS * 3;
    const int cbase = c * CHUNK;

    // Stage this block's chunk of the "other" set, prescaled.
    if (pass == 0) {
        for (int i = t; i < CHUNK; i += BLK) {
            int gi = cbase + i;
            float gx = g[gi * 3 + 0], gy = g[gi * 3 + 1], gz = g[gi * 3 + 2];
            s[i] = make_float4(-2.f * gx, -2.f * gy, -2.f * gz,
                               fmaf(gx, gx, fmaf(gy, gy, gz * gz)));
        }
    } else {
        for (int i = t; i < CHUNK; i += BLK) {
            int pi = cbase + i;
            float px = p[pi], py = p[NPTS + pi], pz = p[2 * NPTS + pi];
            s[i] = make_float4(-2.f * px, -2.f * py, -2.f * pz,
                               fmaf(px, px, fmaf(py, py, pz * pz)));
        }
    }

    // Own points (4 per thread, strided by BLK -> coalesced loads/stores).
    float x[P], y[P], z[P], n2[P];
    #pragma unroll
    for (int k = 0; k < P; ++k) {
        int idx = j * OWN_PER_BLK + k * BLK + t;
        if (pass == 0) {
            x[k] = p[idx]; y[k] = p[NPTS + idx]; z[k] = p[2 * NPTS + idx];
        } else {
            x[k] = g[idx * 3 + 0]; y[k] = g[idx * 3 + 1]; z[k] = g[idx * 3 + 2];
        }
        n2[k] = fmaf(x[k], x[k], fmaf(y[k], y[k], z[k] * z[k]));
    }
    __syncthreads();

    // 2 min accumulators per own point -> 8 independent min chains.
    float ma[P], mb_[P];
    #pragma unroll
    for (int k = 0; k < P; ++k) { ma[k] = 3.4e38f; mb_[k] = 3.4e38f; }

    #pragma unroll 2
    for (int mm = 0; mm < CHUNK; mm += 4) {
        float4 q0 = s[mm + 0];
        float4 q1 = s[mm + 1];
        float4 q2 = s[mm + 2];
        float4 q3 = s[mm + 3];
        #pragma unroll
        for (int k = 0; k < P; ++k) {
            ma[k]  = fminf(ma[k],  fmaf(x[k], q0.x, fmaf(y[k], q0.y, fmaf(z[k], q0.z, q0.w))));
            mb_[k] = fminf(mb_[k], fmaf(x[k], q1.x, fmaf(y[k], q1.y, fmaf(z[k], q1.z, q1.w))));
            ma[k]  = fminf(ma[k],  fmaf(x[k], q2.x, fmaf(y[k], q2.y, fmaf(z[k], q2.z, q2.w))));
            mb_[k] = fminf(mb_[k], fmaf(x[k], q3.x, fmaf(y[k], q3.y, fmaf(z[k], q3.z, q3.w))));
        }
    }

    #pragma unroll
    for (int k = 0; k < P; ++k) {
        int idx = j * OWN_PER_BLK + k * BLK + t;
        int o = pass * HALF_OWN + b * NPTS + idx;
        partial[(size_t)c * TOTAL_OWN + o] = n2[k] + fminf(ma[k], mb_[k]);
    }
}

// Min over chunks per own point, then block partial sums.
__global__ __launch_bounds__(BLK) void chamfer_combine_kernel(
    const float* __restrict__ partial, float* __restrict__ bsum)
{
    __shared__ float red[BLK / 64];
    const int t = threadIdx.x;
    const int o = blockIdx.x * BLK + t;
    float v = 3.4e38f;
    #pragma unroll
    for (int c = 0; c < NCHUNK; ++c)
        v = fminf(v, partial[(size_t)c * TOTAL_OWN + o]);
    #pragma unroll
    for (int off = 32; off > 0; off >>= 1)
        v += __shfl_down(v, off, 64);
    if ((t & 63) == 0) red[t >> 6] = v;
    __syncthreads();
    if (t == 0) bsum[blockIdx.x] = red[0] + red[1] + red[2] + red[3];
}

__global__ __launch_bounds__(COMBINE_BLOCKS) void chamfer_final_kernel(
    const float* __restrict__ bsum, float* __restrict__ out)
{
    __shared__ float red[COMBINE_BLOCKS / 64];
    const int t = threadIdx.x;
    float v = bsum[t];
    #pragma unroll
    for (int off = 32; off > 0; off >>= 1)
        v += __shfl_down(v, off, 64);
    if ((t & 63) == 0) red[t >> 6] = v;
    __syncthreads();
    if (t == 0) {
        float s = 0.f;
        #pragma unroll
        for (int w = 0; w < COMBINE_BLOCKS / 64; ++w) s += red[w];
        // loss = (sum of all mins) / (NPTS * BATCH)   (N == M)
        out[0] = s * (1.0f / ((float)NPTS * (float)BATCH));
    }
}

extern "C" void kernel_launch(void* const* d_in, const int* in_sizes, int n_in,
                              void* d_out, int out_size, void* d_ws, size_t ws_size,
                              hipStream_t stream) {
    const float* pred = (const float*)d_in[0];  // [8,3,4096]
    const float* gt   = (const float*)d_in[1];  // [8,4096,3]
    float* out = (float*)d_out;

    float* partial = (float*)d_ws;                                  // 8*65536 floats = 2 MB
    float* bsum    = partial + (size_t)NCHUNK * TOTAL_OWN;          // 256 floats

    chamfer_partial_kernel<<<TOTAL_BLOCKS, BLK, 0, stream>>>(pred, gt, partial);
    chamfer_combine_kernel<<<COMBINE_BLOCKS, BLK, 0, stream>>>(partial, bsum);
    chamfer_final_kernel<<<1, COMBINE_BLOCKS, 0, stream>>>(bsum, out);
}